// Round 8
// baseline (1212.705 us; speedup 1.0000x reference)
//
#include <hip/hip_runtime.h>
#include <hip/hip_bf16.h>
#include <stdint.h>

#define SEQ     4096
#define DMODEL  2048
#define NHEADS  16
#define DHEAD   128
#define QBLK    256
#define CHUNK   128
#define NCHUNK  (SEQ / CHUNK)

typedef __bf16 bf16_t;
typedef bf16_t bf16x8 __attribute__((ext_vector_type(8)));
typedef bf16_t bf16x4 __attribute__((ext_vector_type(4)));
typedef float  f32x4  __attribute__((ext_vector_type(4)));

typedef __attribute__((address_space(3))) uint32_t       lds_u32_t;
typedef __attribute__((address_space(1))) const uint32_t glb_u32_t;

static __device__ __forceinline__ void gload16(const void* g, void* l) {
  __builtin_amdgcn_global_load_lds((glb_u32_t*)g, (lds_u32_t*)l, 16, 0, 0);
}

// native exp2 (v_exp_f32); s_nop guards the trans->VALU hazard
static __device__ __forceinline__ float exp2_fast(float x) {
  float r;
  asm("v_exp_f32 %0, %1\n\ts_nop 0" : "=v"(r) : "v"(x));
  return r;
}

static __device__ __forceinline__ f32x4 vmax4(f32x4 a, f32x4 b) {
  f32x4 r;
  r[0] = fmaxf(a[0], b[0]); r[1] = fmaxf(a[1], b[1]);
  r[2] = fmaxf(a[2], b[2]); r[3] = fmaxf(a[3], b[3]);
  return r;
}

// legacy swizzle for the fallback kernel + epilogue
__device__ __forceinline__ uint32_t swz(int row, int colbyte) {
  return ((uint32_t)(row * 256 + colbyte)) ^ ((uint32_t)(row & 15) << 4);
}

// ---------------- prepass: K -> bf16 head-major [bh][s][128] ----------------
__global__ __launch_bounds__(256)
void prep_k(const float* __restrict__ kk, bf16_t* __restrict__ kb) {
  const size_t e = ((size_t)blockIdx.x * 256 + threadIdx.x) * 8;
  const int dm = (int)(e % DMODEL);
  const int s  = (int)((e / DMODEL) % SEQ);
  const int b  = (int)(e / ((size_t)DMODEL * SEQ));
  float4 x0 = *(const float4*)(kk + e);
  float4 x1 = *(const float4*)(kk + e + 4);
  bf16x8 y;
  y[0]=(bf16_t)x0.x; y[1]=(bf16_t)x0.y; y[2]=(bf16_t)x0.z; y[3]=(bf16_t)x0.w;
  y[4]=(bf16_t)x1.x; y[5]=(bf16_t)x1.y; y[6]=(bf16_t)x1.z; y[7]=(bf16_t)x1.w;
  const size_t out = (((size_t)(b * NHEADS + (dm >> 7)) * SEQ + s) << 7) + (dm & 127);
  *(bf16x8*)(kb + out) = y;
}

// ---------------- prepass: V -> bf16 transposed [bh][dh][s] ----------------
__global__ __launch_bounds__(256)
void prep_v(const float* __restrict__ vv, bf16_t* __restrict__ vb) {
  __shared__ bf16_t T[128 * 132];
  const int t = threadIdx.x;
  const int s0 = blockIdx.x * 128, h = blockIdx.y, b = blockIdx.z;
  const float* src = vv + ((size_t)(b * SEQ + s0)) * DMODEL + h * DHEAD;
#pragma unroll
  for (int p = 0; p < 16; ++p) {
    const int sr = p * 8 + (t >> 5), c4 = (t & 31) * 4;
    float4 x = *(const float4*)(src + (size_t)sr * DMODEL + c4);
    bf16_t* d = T + sr * 132 + c4;
    d[0]=(bf16_t)x.x; d[1]=(bf16_t)x.y; d[2]=(bf16_t)x.z; d[3]=(bf16_t)x.w;
  }
  __syncthreads();
  bf16_t* out = vb + ((size_t)(b * NHEADS + h)) * DHEAD * SEQ;
#pragma unroll
  for (int p = 0; p < 8; ++p) {
    const int d = p * 16 + (t >> 4), sc8 = (t & 15) * 8;
    bf16x8 y;
#pragma unroll
    for (int j = 0; j < 8; ++j) y[j] = T[(sc8 + j) * 132 + d];
    *(bf16x8*)(out + (size_t)d * SEQ + s0 + sc8) = y;
  }
}

// ------------- main: chunk-pipelined FA (QK(c+1) overlaps softmax(c)) -------------
// Faithful reference quirks: total scale 1/128 (log2-domain: log2e/128);
// p = exp(s - m_chunk), chunk-local max over exactly 128 keys; o,l rescaled by
// exp(m_old-m_new); out = o/(l+1e-6). Chunks strictly in order.
//
// LDS 96KB: Kbuf0 @0 (32KB), Kbuf1 @32K, V @64K. K double-buffered so QK of
// chunk c+1 (MFMA) can be co-scheduled with softmax of chunk c (VALU) -- the
// two are independent; scores ping-pong between sA*/sB* register sets.
// Per iter: [vmcnt(0),bar] -> QK(c+1)||softmax(c) -> PV(c) -> [lgkm(0),bar]
//           -> stage K(c+2),V(c+1).   8 gloads/wave/iter, waits exact.
__global__ __launch_bounds__(512, 1)
void fa_fwd_p(const float* __restrict__ qg, const bf16_t* __restrict__ kbg,
              const bf16_t* __restrict__ vbg, float* __restrict__ og)
{
  __shared__ char smem[98304];

  const int tid  = threadIdx.x;
  const int wave = tid >> 6;
  const int lane = tid & 63;
  const int l15  = lane & 15;
  const int lhi  = lane >> 4;

  // T1: bijective XCD swizzle (nwg = 16*16*B, %8==0)
  const int nwg = gridDim.x * gridDim.y * gridDim.z;
  const int lin = blockIdx.x + gridDim.x * (blockIdx.y + gridDim.y * blockIdx.z);
  const int wg  = (lin % 8) * (nwg / 8) + lin / 8;
  const int bx  = wg % gridDim.x;
  const int h   = (wg / gridDim.x) % NHEADS;
  const int b   = wg / (gridDim.x * NHEADS);
  const int bh  = b * NHEADS + h;
  const int qrow0 = bx * QBLK + wave * 32;

  const bf16_t* kcb = kbg + ((size_t)bh * SEQ) * DHEAD;   // [key][128]
  const bf16_t* vcb = vbg + ((size_t)bh * DHEAD) * SEQ;   // [dh][SEQ]

  // stage a full 32KB K chunk at koff: 4 loads/wave; rows 256B, gx swizzle
#define ISSUE_K(koff, key0)                                                    \
  {                                                                            \
    _Pragma("unroll")                                                          \
    for (int u = 0; u < 4; ++u) {                                              \
      const int row = u * 32 + wave * 4 + (lane >> 4);                         \
      const int gx  = (row & 3) | (((row >> 3) & 3) << 2);                     \
      gload16(kcb + (size_t)((key0) + row) * 128 + (((lane & 15) ^ gx) * 8),   \
              smem + (koff) + u * 8192 + wave * 1024);                         \
    }                                                                          \
  }
  // stage the 32KB V chunk @64K: 4 loads/wave; rows 256B [dh][128key], dh&15 swz
#define ISSUE_V(key0)                                                          \
  {                                                                            \
    _Pragma("unroll")                                                          \
    for (int u = 0; u < 4; ++u) {                                              \
      const int dh = u * 32 + wave * 4 + (lane >> 4);                          \
      gload16(vcb + (size_t)dh * SEQ + (key0) + (((lane & 15) ^ (dh & 15)) * 8),\
              smem + 65536 + u * 8192 + wave * 1024);                          \
    }                                                                          \
  }

  // ---- Q fragments first (their loads drain before any gload_lds is issued)
  bf16x8 qa[8];
  {
    const float sc = 1.4426950408889634f / 128.0f;
#pragma unroll
    for (int h2 = 0; h2 < 2; ++h2) {
      const float* qp =
          qg + ((size_t)(b * SEQ + qrow0 + h2 * 16 + l15)) * DMODEL + h * DHEAD;
#pragma unroll
      for (int kb = 0; kb < 4; ++kb) {
        const float* p8 = qp + kb * 32 + lhi * 8;
        float4 x0 = *(const float4*)p8;
        float4 x1 = *(const float4*)(p8 + 4);
        bf16x8 a;
        a[0] = (bf16_t)(x0.x * sc); a[1] = (bf16_t)(x0.y * sc);
        a[2] = (bf16_t)(x0.z * sc); a[3] = (bf16_t)(x0.w * sc);
        a[4] = (bf16_t)(x1.x * sc); a[5] = (bf16_t)(x1.y * sc);
        a[6] = (bf16_t)(x1.z * sc); a[7] = (bf16_t)(x1.w * sc);
        qa[h2 * 4 + kb] = a;
      }
    }
  }

  // QK of one chunk: fills S0[8] (half0) and S1[8] (half1); kf shared by halves
#define QK_STEP(S0A, S1A, KOFF)                                                \
  {                                                                            \
    __builtin_amdgcn_s_setprio(1);                                             \
    _Pragma("unroll")                                                          \
    for (int t = 0; t < 2; ++t) {                                              \
      const char* Kt = smem + (KOFF) + t * 16384;                              \
      _Pragma("unroll")                                                        \
      for (int nl = 0; nl < 4; ++nl) {                                         \
        const int rowA = (nl >> 1) * 32 + (l15 >> 2) * 8 + (nl & 1) * 4 + (l15 & 3); \
        const int gx   = (rowA & 3) | (((rowA >> 3) & 3) << 2);                \
        f32x4 a0 = {0.f, 0.f, 0.f, 0.f};                                       \
        f32x4 a1 = {0.f, 0.f, 0.f, 0.f};                                       \
        _Pragma("unroll")                                                      \
        for (int j = 0; j < 4; ++j) {                                          \
          const uint32_t byte = (uint32_t)(rowA * 256) +                       \
                                ((j * 64 + lhi * 16) ^ (gx << 4));             \
          bf16x8 kf = *(const bf16x8*)(Kt + byte);                             \
          a0 = __builtin_amdgcn_mfma_f32_16x16x32_bf16(kf, qa[j], a0, 0, 0, 0);\
          a1 = __builtin_amdgcn_mfma_f32_16x16x32_bf16(kf, qa[4 + j], a1, 0, 0, 0);\
        }                                                                      \
        S0A[t * 4 + nl] = a0;                                                  \
        S1A[t * 4 + nl] = a1;                                                  \
      }                                                                        \
    }                                                                          \
    __builtin_amdgcn_s_setprio(0);                                             \
  }

  // softmax of one half (log2 domain, tree reductions, exact skip when e==1)
#define SOFTMAX_HALF(SA, PA, MRUN, LRUN, OBASE)                                \
    {                                                                          \
      f32x4 t0 = vmax4(SA[0], SA[1]), t1 = vmax4(SA[2], SA[3]);                \
      f32x4 t2 = vmax4(SA[4], SA[5]), t3 = vmax4(SA[6], SA[7]);                \
      f32x4 t4 = vmax4(vmax4(t0, t1), vmax4(t2, t3));                          \
      float mc = fmaxf(fmaxf(fmaxf(t4[0], t4[1]), t4[2]), t4[3]);              \
      mc = fmaxf(mc, __shfl_xor(mc, 16, 64));                                  \
      mc = fmaxf(mc, __shfl_xor(mc, 32, 64));                                  \
      const bool skip = __all(mc <= MRUN);                                     \
      const float mn = fmaxf(MRUN, mc);                                        \
      const float e  = exp2_fast(MRUN - mn);                                   \
      MRUN = mn;                                                               \
      f32x4 pe[8];                                                             \
      _Pragma("unroll")                                                        \
      for (int nt = 0; nt < 8; ++nt)                                           \
        _Pragma("unroll")                                                      \
        for (int r = 0; r < 4; ++r) {                                          \
          const float p = exp2_fast(SA[nt][r] - mc);                           \
          pe[nt][r] = p;                                                       \
          PA[(nt >> 2) * 2 + ((nt >> 1) & 1)][(nt & 1) * 4 + r] = (bf16_t)p;   \
        }                                                                      \
      f32x4 q0 = pe[0] + pe[1], q1 = pe[2] + pe[3];                            \
      f32x4 q2 = pe[4] + pe[5], q3 = pe[6] + pe[7];                            \
      f32x4 q4 = (q0 + q1) + (q2 + q3);                                        \
      float ps = (q4[0] + q4[1]) + (q4[2] + q4[3]);                            \
      ps += __shfl_xor(ps, 16, 64);                                            \
      ps += __shfl_xor(ps, 32, 64);                                            \
      if (skip) {                                                              \
        LRUN += ps;                                                            \
      } else {                                                                 \
        LRUN = LRUN * e + ps;                                                  \
        _Pragma("unroll")                                                      \
        for (int r = 0; r < 4; ++r) {                                          \
          const float er = __shfl(e, lhi * 4 + r, 16);                         \
          _Pragma("unroll")                                                    \
          for (int nt = 0; nt < 8; ++nt) oacc[(OBASE) + nt][r] *= er;          \
        }                                                                      \
      }                                                                        \
    }

  // PV of the current chunk from pa0/pa1; vf shared by halves
#define PV_STEP()                                                              \
  {                                                                            \
    __builtin_amdgcn_s_setprio(1);                                             \
    _Pragma("unroll")                                                          \
    for (int kv = 0; kv < 4; ++kv) {                                           \
      _Pragma("unroll")                                                        \
      for (int nt = 0; nt < 8; ++nt) {                                         \
        const int dh = nt * 16 + l15;                                          \
        const uint32_t byte = (uint32_t)(65536 + dh * 256) +                   \
            (((uint32_t)(kv * 64 + lhi * 16)) ^ ((dh & 15) << 4));             \
        bf16x8 vf = *(const bf16x8*)(smem + byte);                             \
        oacc[nt]     = __builtin_amdgcn_mfma_f32_16x16x32_bf16(pa0[kv], vf, oacc[nt], 0, 0, 0);      \
        oacc[8 + nt] = __builtin_amdgcn_mfma_f32_16x16x32_bf16(pa1[kv], vf, oacc[8 + nt], 0, 0, 0);  \
      }                                                                        \
    }                                                                          \
    __builtin_amdgcn_s_setprio(0);                                             \
  }

  // one pipeline iteration for chunk c
#define PIPE_ITER(c, SC0, SC1, SN0, SN1, KNEXT_OFF, KSTAGE_OFF)                \
  {                                                                            \
    asm volatile("s_waitcnt vmcnt(0)\n\ts_barrier" ::: "memory");              \
    if ((c) + 1 < NCHUNK) QK_STEP(SN0, SN1, KNEXT_OFF);                        \
    bf16x8 pa0[4], pa1[4];                                                     \
    SOFTMAX_HALF(SC0, pa0, m_run0, l_run0, 0)                                  \
    SOFTMAX_HALF(SC1, pa1, m_run1, l_run1, 8)                                  \
    PV_STEP();                                                                 \
    asm volatile("s_waitcnt lgkmcnt(0)\n\ts_barrier" ::: "memory");            \
    if ((c) + 2 < NCHUNK) ISSUE_K(KSTAGE_OFF, ((c) + 2) * CHUNK);              \
    if ((c) + 1 < NCHUNK) ISSUE_V(((c) + 1) * CHUNK);                          \
  }

  f32x4 oacc[16];
#pragma unroll
  for (int nt = 0; nt < 16; ++nt) { f32x4 z = {0.f,0.f,0.f,0.f}; oacc[nt] = z; }
  float m_run0 = -INFINITY, l_run0 = 0.f;   // log2-domain, per lane (qrow=l15)
  float m_run1 = -INFINITY, l_run1 = 0.f;

  f32x4 sA0[8], sA1[8], sB0[8], sB1[8];

  // prologue: stage chunk 0; compute QK(0); stage K(1)
  ISSUE_K(0, 0);
  ISSUE_V(0);
  asm volatile("s_waitcnt vmcnt(4)\n\ts_barrier" ::: "memory");  // K(0) landed
  ISSUE_K(32768, CHUNK);          // K(1) -> Kbuf1 (overlaps QK(0))
  QK_STEP(sA0, sA1, 0);           // scores(0) from Kbuf0

  for (int c = 0; c < NCHUNK; c += 2) {
    PIPE_ITER(c,     sA0, sA1, sB0, sB1, 32768, 0);      // QK(c+1) from Kbuf1, stage K(c+2)->Kbuf0
    PIPE_ITER(c + 1, sB0, sB1, sA0, sA1, 0,     32768);  // QK(c+2) from Kbuf0, stage K(c+3)->Kbuf1
  }

  // ---- epilogue: per-wave LDS transpose -> coalesced f32x4 stores, 2 passes
  {
    char* Ow = smem + wave * 8192;  // 16 rows x 512B per pass
#pragma unroll
    for (int h2 = 0; h2 < 2; ++h2) {
      const float lrl = h2 ? l_run1 : l_run0;
      float lr[4];
#pragma unroll
      for (int r = 0; r < 4; ++r) lr[r] = __shfl(lrl, lhi * 4 + r, 16);
#pragma unroll
      for (int nt = 0; nt < 8; ++nt)
#pragma unroll
        for (int r = 0; r < 4; ++r) {
          const int row = lhi * 4 + r;
          const int colb = (nt * 16 + l15) * 4;
          *(float*)(Ow + row * 512 + (colb ^ ((row & 7) << 4))) =
              oacc[h2 * 8 + nt][r] / (lr[r] + 1e-6f);
        }
      asm volatile("s_waitcnt lgkmcnt(0)" ::: "memory");  // wave-local only
      __builtin_amdgcn_sched_barrier(0);
#pragma unroll
      for (int p = 0; p < 8; ++p) {
        const int row = p * 2 + (lane >> 5);
        const int colb = (lane & 31) * 16;
        f32x4 val = *(const f32x4*)(Ow + row * 512 + (colb ^ ((row & 7) << 4)));
        *(f32x4*)((char*)(og + ((size_t)(b * SEQ + qrow0 + h2 * 16 + row)) * DMODEL +
                          h * DHEAD) + colb) = val;
      }
      asm volatile("s_waitcnt lgkmcnt(0)" ::: "memory");  // reads done before reuse
      __builtin_amdgcn_sched_barrier(0);
    }
  }
#undef PIPE_ITER
#undef PV_STEP
#undef SOFTMAX_HALF
#undef QK_STEP
#undef ISSUE_K
#undef ISSUE_V
}

// ---------------- fallback (R2-proven): used if ws too small ----------------
__global__ __launch_bounds__(512, 2)
void fa_fwd_raw(const float* __restrict__ qg, const float* __restrict__ kg,
                const float* __restrict__ vg, float* __restrict__ og)
{
  __shared__ bf16_t Kl[CHUNK * DHEAD];
  __shared__ bf16_t Vt[DHEAD * CHUNK];
  const int tid = threadIdx.x, wave = tid >> 6, lane = tid & 63;
  const int l15 = lane & 15, lhi = lane >> 4;
  const int b = blockIdx.z, h = blockIdx.y;
  const int qrow0 = blockIdx.x * 128 + wave * 16;
  bf16x8 qa[4];
  {
    const float* qp = qg + ((size_t)(b * SEQ + qrow0 + l15)) * DMODEL + h * DHEAD;
    const float sc = 1.0f / 128.0f;
#pragma unroll
    for (int kb = 0; kb < 4; ++kb) {
      const float* p8 = qp + kb * 32 + lhi * 8;
      float4 x0 = *(const float4*)p8; float4 x1 = *(const float4*)(p8 + 4);
      bf16x8 a;
      a[0]=(bf16_t)(x0.x*sc); a[1]=(bf16_t)(x0.y*sc); a[2]=(bf16_t)(x0.z*sc); a[3]=(bf16_t)(x0.w*sc);
      a[4]=(bf16_t)(x1.x*sc); a[5]=(bf16_t)(x1.y*sc); a[6]=(bf16_t)(x1.z*sc); a[7]=(bf16_t)(x1.w*sc);
      qa[kb] = a;
    }
  }
  f32x4 oacc[8];
#pragma unroll
  for (int nt = 0; nt < 8; ++nt) { f32x4 z = {0.f,0.f,0.f,0.f}; oacc[nt] = z; }
  float m_run[4] = {-INFINITY,-INFINITY,-INFINITY,-INFINITY};
  float l_run[4] = {0.f,0.f,0.f,0.f};
  const float* kbp = kg + ((size_t)b * SEQ) * DMODEL + h * DHEAD;
  const float* vbp = vg + ((size_t)b * SEQ) * DMODEL + h * DHEAD;
  const int krow16 = tid >> 5, kc4 = (tid & 31) * 4;
  const int vdh = tid & 127, vkg = (tid >> 7) * 8;
  for (int c = 0; c < NCHUNK; ++c) {
    const int key0 = c * CHUNK;
#pragma unroll
    for (int pass = 0; pass < 8; ++pass) {
      const int key = pass * 16 + krow16;
      const float4 x = *(const float4*)(kbp + (size_t)(key0 + key) * DMODEL + kc4);
      bf16x4 y; y[0]=(bf16_t)x.x; y[1]=(bf16_t)x.y; y[2]=(bf16_t)x.z; y[3]=(bf16_t)x.w;
      *(bf16x4*)((char*)Kl + swz(key, kc4 * 2)) = y;
    }
#pragma unroll
    for (int it = 0; it < 4; ++it) {
      const int kb0 = it * 32 + vkg;
      const float* vp = vbp + (size_t)(key0 + kb0) * DMODEL + vdh;
      bf16x8 y;
#pragma unroll
      for (int j = 0; j < 8; ++j) y[j] = (bf16_t)vp[(size_t)j * DMODEL];
      *(bf16x8*)((char*)Vt + swz(vdh, kb0 * 2)) = y;
    }
    __syncthreads();
    f32x4 sacc[8];
#pragma unroll
    for (int nt = 0; nt < 8; ++nt) {
      f32x4 acc = {0.f,0.f,0.f,0.f};
      const int key = nt * 16 + l15;
#pragma unroll
      for (int kb = 0; kb < 4; ++kb) {
        bf16x8 bfr = *(const bf16x8*)((const char*)Kl + swz(key, (kb*32+lhi*8)*2));
        acc = __builtin_amdgcn_mfma_f32_16x16x32_bf16(qa[kb], bfr, acc, 0, 0, 0);
      }
      sacc[nt] = acc;
    }
    __syncthreads();
    float mc[4];
#pragma unroll
    for (int r = 0; r < 4; ++r) {
      float m0 = sacc[0][r];
#pragma unroll
      for (int nt = 1; nt < 8; ++nt) m0 = fmaxf(m0, sacc[nt][r]);
      mc[r] = m0;
    }
#pragma unroll
    for (int sh = 1; sh < 16; sh <<= 1)
#pragma unroll
      for (int r = 0; r < 4; ++r) mc[r] = fmaxf(mc[r], __shfl_xor(mc[r], sh, 64));
    float esc[4], psum[4];
#pragma unroll
    for (int r = 0; r < 4; ++r) {
      const float mn = fmaxf(m_run[r], mc[r]);
      esc[r] = __expf(m_run[r] - mn); m_run[r] = mn; psum[r] = 0.f;
    }
    bf16_t* Pw = Kl + wave * (16 * 128);
#pragma unroll
    for (int nt = 0; nt < 8; ++nt)
#pragma unroll
      for (int r = 0; r < 4; ++r) {
        const float p = __expf(sacc[nt][r] - mc[r]);
        psum[r] += p;
        const int row = lhi * 4 + r;
        *(bf16_t*)((char*)Pw + swz(row, (nt*16+l15)*2)) = (bf16_t)p;
      }
#pragma unroll
    for (int sh = 1; sh < 16; sh <<= 1)
#pragma unroll
      for (int r = 0; r < 4; ++r) psum[r] += __shfl_xor(psum[r], sh, 64);
#pragma unroll
    for (int r = 0; r < 4; ++r) l_run[r] = l_run[r] * esc[r] + psum[r];
#pragma unroll
    for (int nt = 0; nt < 8; ++nt) {
      f32x4 o = oacc[nt];
      o[0]*=esc[0]; o[1]*=esc[1]; o[2]*=esc[2]; o[3]*=esc[3];
      oacc[nt] = o;
    }
    asm volatile("s_waitcnt lgkmcnt(0)" ::: "memory");
    __builtin_amdgcn_sched_barrier(0);
#pragma unroll
    for (int kb = 0; kb < 4; ++kb) {
      bf16x8 pf = *(const bf16x8*)((const char*)Pw + swz(l15, (kb*32+lhi*8)*2));
#pragma unroll
      for (int nt = 0; nt < 8; ++nt) {
        const int dh = nt * 16 + l15;
        bf16x8 vf = *(const bf16x8*)((const char*)Vt + swz(dh, (kb*32+lhi*8)*2));
        oacc[nt] = __builtin_amdgcn_mfma_f32_16x16x32_bf16(pf, vf, oacc[nt], 0, 0, 0);
      }
    }
    __syncthreads();
  }
#pragma unroll
  for (int nt = 0; nt < 8; ++nt)
#pragma unroll
    for (int r = 0; r < 4; ++r) {
      const int row = lhi * 4 + r;
      og[((size_t)(b * SEQ + qrow0 + row)) * DMODEL + h * DHEAD + nt * 16 + l15] =
          oacc[nt][r] / (l_run[r] + 1e-6f);
    }
}

extern "C" void kernel_launch(void* const* d_in, const int* in_sizes, int n_in,
                              void* d_out, int out_size, void* d_ws, size_t ws_size,
                              hipStream_t stream) {
  const float* q = (const float*)d_in[0];
  const float* k = (const float*)d_in[1];
  const float* v = (const float*)d_in[2];
  float* o = (float*)d_out;
  const int B = in_sizes[0] / (SEQ * DMODEL);
  const size_t kv_bytes = (size_t)B * NHEADS * SEQ * DHEAD * 2;  // 33.5MB @ B=2
  if (ws_size >= 2 * kv_bytes) {
    bf16_t* kb = (bf16_t*)d_ws;
    bf16_t* vb = (bf16_t*)((char*)d_ws + kv_bytes);
    const int nthr = (int)(((size_t)B * SEQ * DMODEL) / 8);
    prep_k<<<nthr / 256, 256, 0, stream>>>(k, kb);
    dim3 gv(SEQ / 128, NHEADS, B);
    prep_v<<<gv, 256, 0, stream>>>(v, vb);
    dim3 grid(SEQ / QBLK, NHEADS, B);
    fa_fwd_p<<<grid, 512, 0, stream>>>(q, kb, vb, o);
  } else {
    dim3 grid(SEQ / 128, NHEADS, B);
    fa_fwd_raw<<<grid, 512, 0, stream>>>(q, k, v, o);
  }
}

// Round 9
// 1006.268 us; speedup vs baseline: 1.2052x; 1.2052x over previous
//
#include <hip/hip_runtime.h>
#include <hip/hip_bf16.h>
#include <stdint.h>

#define SEQ     4096
#define DMODEL  2048
#define NHEADS  16
#define DHEAD   128
#define QBLK    256
#define CHUNK   128
#define NCHUNK  (SEQ / CHUNK)

typedef __bf16 bf16_t;
typedef bf16_t bf16x8 __attribute__((ext_vector_type(8)));
typedef bf16_t bf16x4 __attribute__((ext_vector_type(4)));
typedef float  f32x4  __attribute__((ext_vector_type(4)));

typedef __attribute__((address_space(3))) uint32_t       lds_u32_t;
typedef __attribute__((address_space(1))) const uint32_t glb_u32_t;

static __device__ __forceinline__ void gload16(const void* g, void* l) {
  __builtin_amdgcn_global_load_lds((glb_u32_t*)g, (lds_u32_t*)l, 16, 0, 0);
}

// native exp2 (v_exp_f32); s_nop guards the trans->VALU hazard
static __device__ __forceinline__ float exp2_fast(float x) {
  float r;
  asm("v_exp_f32 %0, %1\n\ts_nop 0" : "=v"(r) : "v"(x));
  return r;
}

static __device__ __forceinline__ f32x4 vmax4(f32x4 a, f32x4 b) {
  f32x4 r;
  r[0] = fmaxf(a[0], b[0]); r[1] = fmaxf(a[1], b[1]);
  r[2] = fmaxf(a[2], b[2]); r[3] = fmaxf(a[3], b[3]);
  return r;
}

// legacy swizzle for the fallback kernel
__device__ __forceinline__ uint32_t swz(int row, int colbyte) {
  return ((uint32_t)(row * 256 + colbyte)) ^ ((uint32_t)(row & 15) << 4);
}

// ---------------- prepass: K -> bf16 head-major [bh][s][128] ----------------
__global__ __launch_bounds__(256)
void prep_k(const float* __restrict__ kk, bf16_t* __restrict__ kb) {
  const size_t e = ((size_t)blockIdx.x * 256 + threadIdx.x) * 8;
  const int dm = (int)(e % DMODEL);
  const int s  = (int)((e / DMODEL) % SEQ);
  const int b  = (int)(e / ((size_t)DMODEL * SEQ));
  float4 x0 = *(const float4*)(kk + e);
  float4 x1 = *(const float4*)(kk + e + 4);
  bf16x8 y;
  y[0]=(bf16_t)x0.x; y[1]=(bf16_t)x0.y; y[2]=(bf16_t)x0.z; y[3]=(bf16_t)x0.w;
  y[4]=(bf16_t)x1.x; y[5]=(bf16_t)x1.y; y[6]=(bf16_t)x1.z; y[7]=(bf16_t)x1.w;
  const size_t out = (((size_t)(b * NHEADS + (dm >> 7)) * SEQ + s) << 7) + (dm & 127);
  *(bf16x8*)(kb + out) = y;
}

// ---------------- prepass: V -> bf16 transposed [bh][dh][s] ----------------
__global__ __launch_bounds__(256)
void prep_v(const float* __restrict__ vv, bf16_t* __restrict__ vb) {
  __shared__ bf16_t T[128 * 132];
  const int t = threadIdx.x;
  const int s0 = blockIdx.x * 128, h = blockIdx.y, b = blockIdx.z;
  const float* src = vv + ((size_t)(b * SEQ + s0)) * DMODEL + h * DHEAD;
#pragma unroll
  for (int p = 0; p < 16; ++p) {
    const int sr = p * 8 + (t >> 5), c4 = (t & 31) * 4;
    float4 x = *(const float4*)(src + (size_t)sr * DMODEL + c4);
    bf16_t* d = T + sr * 132 + c4;
    d[0]=(bf16_t)x.x; d[1]=(bf16_t)x.y; d[2]=(bf16_t)x.z; d[3]=(bf16_t)x.w;
  }
  __syncthreads();
  bf16_t* out = vb + ((size_t)(b * NHEADS + h)) * DHEAD * SEQ;
#pragma unroll
  for (int p = 0; p < 8; ++p) {
    const int d = p * 16 + (t >> 4), sc8 = (t & 15) * 8;
    bf16x8 y;
#pragma unroll
    for (int j = 0; j < 8; ++j) y[j] = T[(sc8 + j) * 132 + d];
    *(bf16x8*)(out + (size_t)d * SEQ + s0 + sc8) = y;
  }
}

// ------- main: single-score-set pipelined FA (SM(c) -> QK(c+1) -> PV(c)) -------
// Faithful reference quirks: total scale 1/128 (log2-domain: log2e/128);
// p = exp(s - m_chunk), chunk-local max over exactly 128 keys; o,l rescaled by
// exp(m_old-m_new); out = o/(l+1e-6). Chunks strictly in order.
//
// LDS 128KB: Kb0 @0, Kb1 @32K, Vb0 @64K, Vb1 @96K (all double-buffered).
// Per iter (ONE barrier-free region -> 2 waves/SIMD drift and overlap):
//   [vmcnt(0),bar] -> issue K(c+2),V(c+1) -> softmax(c) (sacc->pa, sacc dies)
//   -> QK(c+1) writes back into sacc (zero extra registers -- R8's spill fix)
//   -> PV(c) -> [lgkm(0),bar]
// Staged loads get a full iteration in flight before their vmcnt(0).
__global__ __launch_bounds__(512, 1)
void fa_fwd_p(const float* __restrict__ qg, const bf16_t* __restrict__ kbg,
              const bf16_t* __restrict__ vbg, float* __restrict__ og)
{
  __shared__ char smem[131072];

  const int tid  = threadIdx.x;
  const int wave = tid >> 6;
  const int lane = tid & 63;
  const int l15  = lane & 15;
  const int lhi  = lane >> 4;

  // T1: bijective XCD swizzle (nwg = 16*16*B, %8==0)
  const int nwg = gridDim.x * gridDim.y * gridDim.z;
  const int lin = blockIdx.x + gridDim.x * (blockIdx.y + gridDim.y * blockIdx.z);
  const int wg  = (lin % 8) * (nwg / 8) + lin / 8;
  const int bx  = wg % gridDim.x;
  const int h   = (wg / gridDim.x) % NHEADS;
  const int b   = wg / (gridDim.x * NHEADS);
  const int bh  = b * NHEADS + h;
  const int qrow0 = bx * QBLK + wave * 32;

  const bf16_t* kcb = kbg + ((size_t)bh * SEQ) * DHEAD;   // [key][128]
  const bf16_t* vcb = vbg + ((size_t)bh * DHEAD) * SEQ;   // [dh][SEQ]

  // stage a 32KB K chunk at koff: 4 loads/wave; rows 256B, gx swizzle
#define ISSUE_K(koff, key0)                                                    \
  {                                                                            \
    _Pragma("unroll")                                                          \
    for (int u = 0; u < 4; ++u) {                                              \
      const int row = u * 32 + wave * 4 + (lane >> 4);                         \
      const int gx  = (row & 3) | (((row >> 3) & 3) << 2);                     \
      gload16(kcb + (size_t)((key0) + row) * 128 + (((lane & 15) ^ gx) * 8),   \
              smem + (koff) + u * 8192 + wave * 1024);                         \
    }                                                                          \
  }
  // stage a 32KB V chunk at voff: rows 256B [dh][128key], dh&15 swizzle
#define ISSUE_V(voff, key0)                                                    \
  {                                                                            \
    _Pragma("unroll")                                                          \
    for (int u = 0; u < 4; ++u) {                                              \
      const int dh = u * 32 + wave * 4 + (lane >> 4);                          \
      gload16(vcb + (size_t)dh * SEQ + (key0) + (((lane & 15) ^ (dh & 15)) * 8),\
              smem + (voff) + u * 8192 + wave * 1024);                         \
    }                                                                          \
  }

  // ---- Q fragments (plain loads; complete before gload_lds matters)
  bf16x8 qa[8];
  {
    const float sc = 1.4426950408889634f / 128.0f;
#pragma unroll
    for (int h2 = 0; h2 < 2; ++h2) {
      const float* qp =
          qg + ((size_t)(b * SEQ + qrow0 + h2 * 16 + l15)) * DMODEL + h * DHEAD;
#pragma unroll
      for (int kb = 0; kb < 4; ++kb) {
        const float* p8 = qp + kb * 32 + lhi * 8;
        float4 x0 = *(const float4*)p8;
        float4 x1 = *(const float4*)(p8 + 4);
        bf16x8 a;
        a[0] = (bf16_t)(x0.x * sc); a[1] = (bf16_t)(x0.y * sc);
        a[2] = (bf16_t)(x0.z * sc); a[3] = (bf16_t)(x0.w * sc);
        a[4] = (bf16_t)(x1.x * sc); a[5] = (bf16_t)(x1.y * sc);
        a[6] = (bf16_t)(x1.z * sc); a[7] = (bf16_t)(x1.w * sc);
        qa[h2 * 4 + kb] = a;
      }
    }
  }

  // QK of one chunk into s0/s1 (halves share each kf read)
#define QK_STEP(KOFF)                                                          \
  {                                                                            \
    __builtin_amdgcn_s_setprio(1);                                             \
    _Pragma("unroll")                                                          \
    for (int t = 0; t < 2; ++t) {                                              \
      const char* Kt = smem + (KOFF) + t * 16384;                              \
      _Pragma("unroll")                                                        \
      for (int nl = 0; nl < 4; ++nl) {                                         \
        const int rowA = (nl >> 1) * 32 + (l15 >> 2) * 8 + (nl & 1) * 4 + (l15 & 3); \
        const int gx   = (rowA & 3) | (((rowA >> 3) & 3) << 2);                \
        f32x4 a0 = {0.f, 0.f, 0.f, 0.f};                                       \
        f32x4 a1 = {0.f, 0.f, 0.f, 0.f};                                       \
        _Pragma("unroll")                                                      \
        for (int j = 0; j < 4; ++j) {                                          \
          const uint32_t byte = (uint32_t)(rowA * 256) +                       \
                                ((j * 64 + lhi * 16) ^ (gx << 4));             \
          bf16x8 kf = *(const bf16x8*)(Kt + byte);                             \
          a0 = __builtin_amdgcn_mfma_f32_16x16x32_bf16(kf, qa[j], a0, 0, 0, 0);\
          a1 = __builtin_amdgcn_mfma_f32_16x16x32_bf16(kf, qa[4 + j], a1, 0, 0, 0);\
        }                                                                      \
        s0[t * 4 + nl] = a0;                                                   \
        s1[t * 4 + nl] = a1;                                                   \
      }                                                                        \
    }                                                                          \
    __builtin_amdgcn_s_setprio(0);                                             \
  }

  // softmax of one half (log2 domain, tree reductions, exact skip when e==1)
#define SOFTMAX_HALF(SA, PA, MRUN, LRUN, OBASE)                                \
    {                                                                          \
      f32x4 t0 = vmax4(SA[0], SA[1]), t1 = vmax4(SA[2], SA[3]);                \
      f32x4 t2 = vmax4(SA[4], SA[5]), t3 = vmax4(SA[6], SA[7]);                \
      f32x4 t4 = vmax4(vmax4(t0, t1), vmax4(t2, t3));                          \
      float mc = fmaxf(fmaxf(fmaxf(t4[0], t4[1]), t4[2]), t4[3]);              \
      mc = fmaxf(mc, __shfl_xor(mc, 16, 64));                                  \
      mc = fmaxf(mc, __shfl_xor(mc, 32, 64));                                  \
      const bool skip = __all(mc <= MRUN);                                     \
      const float mn = fmaxf(MRUN, mc);                                        \
      const float e  = exp2_fast(MRUN - mn);                                   \
      MRUN = mn;                                                               \
      f32x4 pe[8];                                                             \
      _Pragma("unroll")                                                        \
      for (int nt = 0; nt < 8; ++nt)                                           \
        _Pragma("unroll")                                                      \
        for (int r = 0; r < 4; ++r) {                                          \
          const float p = exp2_fast(SA[nt][r] - mc);                           \
          pe[nt][r] = p;                                                       \
          PA[(nt >> 2) * 2 + ((nt >> 1) & 1)][(nt & 1) * 4 + r] = (bf16_t)p;   \
        }                                                                      \
      f32x4 q0 = pe[0] + pe[1], q1 = pe[2] + pe[3];                            \
      f32x4 q2 = pe[4] + pe[5], q3 = pe[6] + pe[7];                            \
      f32x4 q4 = (q0 + q1) + (q2 + q3);                                        \
      float ps = (q4[0] + q4[1]) + (q4[2] + q4[3]);                            \
      ps += __shfl_xor(ps, 16, 64);                                            \
      ps += __shfl_xor(ps, 32, 64);                                            \
      if (skip) {                                                              \
        LRUN += ps;                                                            \
      } else {                                                                 \
        LRUN = LRUN * e + ps;                                                  \
        _Pragma("unroll")                                                      \
        for (int r = 0; r < 4; ++r) {                                          \
          const float er = __shfl(e, lhi * 4 + r, 16);                         \
          _Pragma("unroll")                                                    \
          for (int nt = 0; nt < 8; ++nt) oacc[(OBASE) + nt][r] *= er;          \
        }                                                                      \
      }                                                                        \
    }

  // PV of the current chunk from pa0/pa1; vf shared by halves
#define PV_STEP(VOFF)                                                          \
  {                                                                            \
    __builtin_amdgcn_s_setprio(1);                                             \
    _Pragma("unroll")                                                          \
    for (int kv = 0; kv < 4; ++kv) {                                           \
      _Pragma("unroll")                                                        \
      for (int nt = 0; nt < 8; ++nt) {                                         \
        const int dh = nt * 16 + l15;                                          \
        const uint32_t byte = (uint32_t)((VOFF) + dh * 256) +                  \
            (((uint32_t)(kv * 64 + lhi * 16)) ^ ((dh & 15) << 4));             \
        bf16x8 vf = *(const bf16x8*)(smem + byte);                             \
        oacc[nt]     = __builtin_amdgcn_mfma_f32_16x16x32_bf16(pa0[kv], vf, oacc[nt], 0, 0, 0);      \
        oacc[8 + nt] = __builtin_amdgcn_mfma_f32_16x16x32_bf16(pa1[kv], vf, oacc[8 + nt], 0, 0, 0);  \
      }                                                                        \
    }                                                                          \
    __builtin_amdgcn_s_setprio(0);                                             \
  }

  // one pipeline iteration for chunk c (compile-time buffer offsets)
#define PIPE_ITER(c, KNEXT, KSTAGE, VCUR, VSTAGE)                              \
  {                                                                            \
    asm volatile("s_waitcnt vmcnt(0)\n\ts_barrier" ::: "memory");              \
    if ((c) + 2 < NCHUNK) ISSUE_K(KSTAGE, ((c) + 2) * CHUNK);                  \
    if ((c) + 1 < NCHUNK) ISSUE_V(VSTAGE, ((c) + 1) * CHUNK);                  \
    bf16x8 pa0[4], pa1[4];                                                     \
    SOFTMAX_HALF(s0, pa0, m_run0, l_run0, 0)                                   \
    SOFTMAX_HALF(s1, pa1, m_run1, l_run1, 8)                                   \
    if ((c) + 1 < NCHUNK) QK_STEP(KNEXT);   /* sacc reused: no extra regs */   \
    PV_STEP(VCUR);                                                             \
    asm volatile("s_waitcnt lgkmcnt(0)\n\ts_barrier" ::: "memory");            \
  }

  f32x4 oacc[16];
#pragma unroll
  for (int nt = 0; nt < 16; ++nt) { f32x4 z = {0.f,0.f,0.f,0.f}; oacc[nt] = z; }
  float m_run0 = -INFINITY, l_run0 = 0.f;   // log2-domain, per lane (qrow=l15)
  float m_run1 = -INFINITY, l_run1 = 0.f;

  f32x4 s0[8], s1[8];

  // prologue: stage K(0)/V(0); QK(0); stage K(1)
  ISSUE_K(0, 0);          // -> Kb0
  ISSUE_V(65536, 0);      // -> Vb0
  asm volatile("s_waitcnt vmcnt(4)\n\ts_barrier" ::: "memory");  // K(0) landed
  ISSUE_K(32768, CHUNK);  // K(1) -> Kb1 (overlaps QK(0))
  QK_STEP(0);             // scores(0) from Kb0

  for (int c = 0; c < NCHUNK; c += 2) {
    PIPE_ITER(c,     32768, 0,     65536, 98304);  // QK(c+1) Kb1; stage K(c+2)->Kb0; V(c)=Vb0; stage V(c+1)->Vb1
    PIPE_ITER(c + 1, 0,     32768, 98304, 65536);  // QK(c+2) Kb0; stage K(c+3)->Kb1; V=Vb1; stage ->Vb0
  }

  // ---- epilogue: per-wave LDS transpose -> coalesced f32x4 stores, 2 passes
  {
    char* Ow = smem + wave * 8192;  // 16 rows x 512B per pass
#pragma unroll
    for (int h2 = 0; h2 < 2; ++h2) {
      const float lrl = h2 ? l_run1 : l_run0;
      float lr[4];
#pragma unroll
      for (int r = 0; r < 4; ++r) lr[r] = __shfl(lrl, lhi * 4 + r, 16);
#pragma unroll
      for (int nt = 0; nt < 8; ++nt)
#pragma unroll
        for (int r = 0; r < 4; ++r) {
          const int row = lhi * 4 + r;
          const int colb = (nt * 16 + l15) * 4;
          *(float*)(Ow + row * 512 + (colb ^ ((row & 7) << 4))) =
              oacc[h2 * 8 + nt][r] / (lr[r] + 1e-6f);
        }
      asm volatile("s_waitcnt lgkmcnt(0)" ::: "memory");  // wave-local only
      __builtin_amdgcn_sched_barrier(0);
#pragma unroll
      for (int p = 0; p < 8; ++p) {
        const int row = p * 2 + (lane >> 5);
        const int colb = (lane & 31) * 16;
        f32x4 val = *(const f32x4*)(Ow + row * 512 + (colb ^ ((row & 7) << 4)));
        *(f32x4*)((char*)(og + ((size_t)(b * SEQ + qrow0 + h2 * 16 + row)) * DMODEL +
                          h * DHEAD) + colb) = val;
      }
      asm volatile("s_waitcnt lgkmcnt(0)" ::: "memory");  // reads done before reuse
      __builtin_amdgcn_sched_barrier(0);
    }
  }
#undef PIPE_ITER
#undef PV_STEP
#undef SOFTMAX_HALF
#undef QK_STEP
#undef ISSUE_K
#undef ISSUE_V
}

// ---------------- fallback (R2-proven): used if ws too small ----------------
__global__ __launch_bounds__(512, 2)
void fa_fwd_raw(const float* __restrict__ qg, const float* __restrict__ kg,
                const float* __restrict__ vg, float* __restrict__ og)
{
  __shared__ bf16_t Kl[CHUNK * DHEAD];
  __shared__ bf16_t Vt[DHEAD * CHUNK];
  const int tid = threadIdx.x, wave = tid >> 6, lane = tid & 63;
  const int l15 = lane & 15, lhi = lane >> 4;
  const int b = blockIdx.z, h = blockIdx.y;
  const int qrow0 = blockIdx.x * 128 + wave * 16;
  bf16x8 qa[4];
  {
    const float* qp = qg + ((size_t)(b * SEQ + qrow0 + l15)) * DMODEL + h * DHEAD;
    const float sc = 1.0f / 128.0f;
#pragma unroll
    for (int kb = 0; kb < 4; ++kb) {
      const float* p8 = qp + kb * 32 + lhi * 8;
      float4 x0 = *(const float4*)p8; float4 x1 = *(const float4*)(p8 + 4);
      bf16x8 a;
      a[0]=(bf16_t)(x0.x*sc); a[1]=(bf16_t)(x0.y*sc); a[2]=(bf16_t)(x0.z*sc); a[3]=(bf16_t)(x0.w*sc);
      a[4]=(bf16_t)(x1.x*sc); a[5]=(bf16_t)(x1.y*sc); a[6]=(bf16_t)(x1.z*sc); a[7]=(bf16_t)(x1.w*sc);
      qa[kb] = a;
    }
  }
  f32x4 oacc[8];
#pragma unroll
  for (int nt = 0; nt < 8; ++nt) { f32x4 z = {0.f,0.f,0.f,0.f}; oacc[nt] = z; }
  float m_run[4] = {-INFINITY,-INFINITY,-INFINITY,-INFINITY};
  float l_run[4] = {0.f,0.f,0.f,0.f};
  const float* kbp = kg + ((size_t)b * SEQ) * DMODEL + h * DHEAD;
  const float* vbp = vg + ((size_t)b * SEQ) * DMODEL + h * DHEAD;
  const int krow16 = tid >> 5, kc4 = (tid & 31) * 4;
  const int vdh = tid & 127, vkg = (tid >> 7) * 8;
  for (int c = 0; c < NCHUNK; ++c) {
    const int key0 = c * CHUNK;
#pragma unroll
    for (int pass = 0; pass < 8; ++pass) {
      const int key = pass * 16 + krow16;
      const float4 x = *(const float4*)(kbp + (size_t)(key0 + key) * DMODEL + kc4);
      bf16x4 y; y[0]=(bf16_t)x.x; y[1]=(bf16_t)x.y; y[2]=(bf16_t)x.z; y[3]=(bf16_t)x.w;
      *(bf16x4*)((char*)Kl + swz(key, kc4 * 2)) = y;
    }
#pragma unroll
    for (int it = 0; it < 4; ++it) {
      const int kb0 = it * 32 + vkg;
      const float* vp = vbp + (size_t)(key0 + kb0) * DMODEL + vdh;
      bf16x8 y;
#pragma unroll
      for (int j = 0; j < 8; ++j) y[j] = (bf16_t)vp[(size_t)j * DMODEL];
      *(bf16x8*)((char*)Vt + swz(vdh, kb0 * 2)) = y;
    }
    __syncthreads();
    f32x4 sacc[8];
#pragma unroll
    for (int nt = 0; nt < 8; ++nt) {
      f32x4 acc = {0.f,0.f,0.f,0.f};
      const int key = nt * 16 + l15;
#pragma unroll
      for (int kb = 0; kb < 4; ++kb) {
        bf16x8 bfr = *(const bf16x8*)((const char*)Kl + swz(key, (kb*32+lhi*8)*2));
        acc = __builtin_amdgcn_mfma_f32_16x16x32_bf16(qa[kb], bfr, acc, 0, 0, 0);
      }
      sacc[nt] = acc;
    }
    __syncthreads();
    float mc[4];
#pragma unroll
    for (int r = 0; r < 4; ++r) {
      float m0 = sacc[0][r];
#pragma unroll
      for (int nt = 1; nt < 8; ++nt) m0 = fmaxf(m0, sacc[nt][r]);
      mc[r] = m0;
    }
#pragma unroll
    for (int sh = 1; sh < 16; sh <<= 1)
#pragma unroll
      for (int r = 0; r < 4; ++r) mc[r] = fmaxf(mc[r], __shfl_xor(mc[r], sh, 64));
    float esc[4], psum[4];
#pragma unroll
    for (int r = 0; r < 4; ++r) {
      const float mn = fmaxf(m_run[r], mc[r]);
      esc[r] = __expf(m_run[r] - mn); m_run[r] = mn; psum[r] = 0.f;
    }
    bf16_t* Pw = Kl + wave * (16 * 128);
#pragma unroll
    for (int nt = 0; nt < 8; ++nt)
#pragma unroll
      for (int r = 0; r < 4; ++r) {
        const float p = __expf(sacc[nt][r] - mc[r]);
        psum[r] += p;
        const int row = lhi * 4 + r;
        *(bf16_t*)((char*)Pw + swz(row, (nt*16+l15)*2)) = (bf16_t)p;
      }
#pragma unroll
    for (int sh = 1; sh < 16; sh <<= 1)
#pragma unroll
      for (int r = 0; r < 4; ++r) psum[r] += __shfl_xor(psum[r], sh, 64);
#pragma unroll
    for (int r = 0; r < 4; ++r) l_run[r] = l_run[r] * esc[r] + psum[r];
#pragma unroll
    for (int nt = 0; nt < 8; ++nt) {
      f32x4 o = oacc[nt];
      o[0]*=esc[0]; o[1]*=esc[1]; o[2]*=esc[2]; o[3]*=esc[3];
      oacc[nt] = o;
    }
    asm volatile("s_waitcnt lgkmcnt(0)" ::: "memory");
    __builtin_amdgcn_sched_barrier(0);
#pragma unroll
    for (int kb = 0; kb < 4; ++kb) {
      bf16x8 pf = *(const bf16x8*)((const char*)Pw + swz(l15, (kb*32+lhi*8)*2));
#pragma unroll
      for (int nt = 0; nt < 8; ++nt) {
        const int dh = nt * 16 + l15;
        bf16x8 vf = *(const bf16x8*)((const char*)Vt + swz(dh, (kb*32+lhi*8)*2));
        oacc[nt] = __builtin_amdgcn_mfma_f32_16x16x32_bf16(pf, vf, oacc[nt], 0, 0, 0);
      }
    }
    __syncthreads();
  }
#pragma unroll
  for (int nt = 0; nt < 8; ++nt)
#pragma unroll
    for (int r = 0; r < 4; ++r) {
      const int row = lhi * 4 + r;
      og[((size_t)(b * SEQ + qrow0 + row)) * DMODEL + h * DHEAD + nt * 16 + l15] =
          oacc[nt][r] / (l_run[r] + 1e-6f);
    }
}

extern "C" void kernel_launch(void* const* d_in, const int* in_sizes, int n_in,
                              void* d_out, int out_size, void* d_ws, size_t ws_size,
                              hipStream_t stream) {
  const float* q = (const float*)d_in[0];
  const float* k = (const float*)d_in[1];
  const float* v = (const float*)d_in[2];
  float* o = (float*)d_out;
  const int B = in_sizes[0] / (SEQ * DMODEL);
  const size_t kv_bytes = (size_t)B * NHEADS * SEQ * DHEAD * 2;  // 33.5MB @ B=2
  if (ws_size >= 2 * kv_bytes) {
    bf16_t* kb = (bf16_t*)d_ws;
    bf16_t* vb = (bf16_t*)((char*)d_ws + kv_bytes);
    const int nthr = (int)(((size_t)B * SEQ * DMODEL) / 8);
    prep_k<<<nthr / 256, 256, 0, stream>>>(k, kb);
    dim3 gv(SEQ / 128, NHEADS, B);
    prep_v<<<gv, 256, 0, stream>>>(v, vb);
    dim3 grid(SEQ / QBLK, NHEADS, B);
    fa_fwd_p<<<grid, 512, 0, stream>>>(q, kb, vb, o);
  } else {
    dim3 grid(SEQ / 128, NHEADS, B);
    fa_fwd_raw<<<grid, 512, 0, stream>>>(q, k, v, o);
  }
}

// Round 10
// 326.944 us; speedup vs baseline: 3.7092x; 3.0778x over previous
//
#include <hip/hip_runtime.h>
#include <hip/hip_bf16.h>
#include <stdint.h>

#define SEQ     4096
#define DMODEL  2048
#define NHEADS  16
#define DHEAD   128
#define QBLK    128     // per block of 4 waves; 32 q-rows per wave
#define CHUNK   128
#define NCHUNK  (SEQ / CHUNK)

typedef __bf16 bf16_t;
typedef bf16_t bf16x8 __attribute__((ext_vector_type(8)));
typedef bf16_t bf16x4 __attribute__((ext_vector_type(4)));
typedef float  f32x4  __attribute__((ext_vector_type(4)));

typedef __attribute__((address_space(3))) uint32_t       lds_u32_t;
typedef __attribute__((address_space(1))) const uint32_t glb_u32_t;

static __device__ __forceinline__ void gload16(const void* g, void* l) {
  __builtin_amdgcn_global_load_lds((glb_u32_t*)g, (lds_u32_t*)l, 16, 0, 0);
}

// native exp2 (v_exp_f32); s_nop guards the trans->VALU hazard
static __device__ __forceinline__ float exp2_fast(float x) {
  float r;
  asm("v_exp_f32 %0, %1\n\ts_nop 0" : "=v"(r) : "v"(x));
  return r;
}

static __device__ __forceinline__ f32x4 vmax4(f32x4 a, f32x4 b) {
  f32x4 r;
  r[0] = fmaxf(a[0], b[0]); r[1] = fmaxf(a[1], b[1]);
  r[2] = fmaxf(a[2], b[2]); r[3] = fmaxf(a[3], b[3]);
  return r;
}

// legacy swizzle for the fallback kernel
__device__ __forceinline__ uint32_t swz(int row, int colbyte) {
  return ((uint32_t)(row * 256 + colbyte)) ^ ((uint32_t)(row & 15) << 4);
}

// ---------------- prepass: K -> bf16 head-major [bh][s][128] ----------------
__global__ __launch_bounds__(256)
void prep_k(const float* __restrict__ kk, bf16_t* __restrict__ kb) {
  const size_t e = ((size_t)blockIdx.x * 256 + threadIdx.x) * 8;
  const int dm = (int)(e % DMODEL);
  const int s  = (int)((e / DMODEL) % SEQ);
  const int b  = (int)(e / ((size_t)DMODEL * SEQ));
  float4 x0 = *(const float4*)(kk + e);
  float4 x1 = *(const float4*)(kk + e + 4);
  bf16x8 y;
  y[0]=(bf16_t)x0.x; y[1]=(bf16_t)x0.y; y[2]=(bf16_t)x0.z; y[3]=(bf16_t)x0.w;
  y[4]=(bf16_t)x1.x; y[5]=(bf16_t)x1.y; y[6]=(bf16_t)x1.z; y[7]=(bf16_t)x1.w;
  const size_t out = (((size_t)(b * NHEADS + (dm >> 7)) * SEQ + s) << 7) + (dm & 127);
  *(bf16x8*)(kb + out) = y;
}

// ---------------- prepass: V -> bf16 transposed [bh][dh][s] ----------------
__global__ __launch_bounds__(256)
void prep_v(const float* __restrict__ vv, bf16_t* __restrict__ vb) {
  __shared__ bf16_t T[128 * 132];
  const int t = threadIdx.x;
  const int s0 = blockIdx.x * 128, h = blockIdx.y, b = blockIdx.z;
  const float* src = vv + ((size_t)(b * SEQ + s0)) * DMODEL + h * DHEAD;
#pragma unroll
  for (int p = 0; p < 16; ++p) {
    const int sr = p * 8 + (t >> 5), c4 = (t & 31) * 4;
    float4 x = *(const float4*)(src + (size_t)sr * DMODEL + c4);
    bf16_t* d = T + sr * 132 + c4;
    d[0]=(bf16_t)x.x; d[1]=(bf16_t)x.y; d[2]=(bf16_t)x.z; d[3]=(bf16_t)x.w;
  }
  __syncthreads();
  bf16_t* out = vb + ((size_t)(b * NHEADS + h)) * DHEAD * SEQ;
#pragma unroll
  for (int p = 0; p < 8; ++p) {
    const int d = p * 16 + (t >> 4), sc8 = (t & 15) * 8;
    bf16x8 y;
#pragma unroll
    for (int j = 0; j < 8; ++j) y[j] = T[(sc8 + j) * 132 + d];
    *(bf16x8*)(out + (size_t)d * SEQ + s0 + sc8) = y;
  }
}

// ------- main: R7 pipeline, 4-wave blocks -> 2 independent blocks per CU -------
// Faithful reference quirks: total scale 1/128 (log2-domain: log2e/128);
// p = exp(s - m_chunk), chunk-local max over exactly 128 keys; o,l rescaled by
// exp(m_old-m_new); out = o/(l+1e-6). Chunks strictly in order.
//
// Per-wave code identical to R7 (proven no-spill, VGPR 112). Block = 4 waves,
// LDS 64KB (KA @0, KB @16K, V @32K) -> 2 blocks/CU co-resident. The two
// blocks drift to different pipeline phases, overlapping one block's softmax
// (VALU) with the other's QK/PV (MFMA+LDS) -- phase overlap via the CU
// scheduler instead of in-wave pipelining (R8/R9 both spilled).
// Loop: QK(c) -> [vmcnt0,bar] -> issue K(c+1) -> softmax -> PV(c)
//       -> [vmcnt0,bar] -> issue V(c+1).  Waits are exact counted drains.
__global__ __launch_bounds__(256, 2)
void fa_fwd_p(const float* __restrict__ qg, const bf16_t* __restrict__ kbg,
              const bf16_t* __restrict__ vbg, float* __restrict__ og)
{
  __shared__ char smem[65536];

  const int tid  = threadIdx.x;
  const int wave = tid >> 6;          // 0..3
  const int lane = tid & 63;
  const int l15  = lane & 15;
  const int lhi  = lane >> 4;

  // T1: bijective XCD swizzle (nwg = 32*16*B = 1024 @ B=2, %8==0)
  const int nwg = gridDim.x * gridDim.y * gridDim.z;
  const int lin = blockIdx.x + gridDim.x * (blockIdx.y + gridDim.y * blockIdx.z);
  const int wg  = (lin % 8) * (nwg / 8) + lin / 8;
  const int bx  = wg % gridDim.x;
  const int h   = (wg / gridDim.x) % NHEADS;
  const int b   = wg / (gridDim.x * NHEADS);
  const int bh  = b * NHEADS + h;
  const int qrow0 = bx * QBLK + wave * 32;

  const bf16_t* kcb = kbg + ((size_t)bh * SEQ) * DHEAD;   // [key][128]
  const bf16_t* vcb = vbg + ((size_t)bh * DHEAD) * SEQ;   // [dh][SEQ]

  // stage a 16KB K half-tile (64 keys) at koff: 4 loads/wave (4 waves)
  // row = u*16 + wave*4 + (lane>>4); rows 256B; gx swizzle (== l15 on read)
#define ISSUE_K(koff, key0)                                                    \
  {                                                                            \
    _Pragma("unroll")                                                          \
    for (int u = 0; u < 4; ++u) {                                              \
      const int row = u * 16 + wave * 4 + (lane >> 4);                         \
      const int gx  = (row & 3) | (((row >> 3) & 3) << 2);                     \
      gload16(kcb + (size_t)((key0) + row) * 128 + (((lane & 15) ^ gx) * 8),   \
              smem + (koff) + u * 4096 + wave * 1024);                         \
    }                                                                          \
  }
  // stage the 32KB V chunk @32K: 8 loads/wave; rows 256B [dh][128key], dh&15 swz
#define ISSUE_V(key0)                                                          \
  {                                                                            \
    _Pragma("unroll")                                                          \
    for (int u = 0; u < 8; ++u) {                                              \
      const int dh = u * 16 + wave * 4 + (lane >> 4);                          \
      gload16(vcb + (size_t)dh * SEQ + (key0) + (((lane & 15) ^ (dh & 15)) * 8),\
              smem + 32768 + u * 4096 + wave * 1024);                          \
    }                                                                          \
  }

  // prologue staging: chunk 0 (K 8 loads, then V 8 loads; vmcnt retires in order)
  ISSUE_K(0, 0);
  ISSUE_K(16384, 64);
  ISSUE_V(0);

  // ---- Q fragments, 2 halves, B-operand layout; scale = log2(e)/128
  bf16x8 qa[8];
  {
    const float sc = 1.4426950408889634f / 128.0f;
#pragma unroll
    for (int h2 = 0; h2 < 2; ++h2) {
      const float* qp =
          qg + ((size_t)(b * SEQ + qrow0 + h2 * 16 + l15)) * DMODEL + h * DHEAD;
#pragma unroll
      for (int kb = 0; kb < 4; ++kb) {
        const float* p8 = qp + kb * 32 + lhi * 8;
        float4 x0 = *(const float4*)p8;
        float4 x1 = *(const float4*)(p8 + 4);
        bf16x8 a;
        a[0] = (bf16_t)(x0.x * sc); a[1] = (bf16_t)(x0.y * sc);
        a[2] = (bf16_t)(x0.z * sc); a[3] = (bf16_t)(x0.w * sc);
        a[4] = (bf16_t)(x1.x * sc); a[5] = (bf16_t)(x1.y * sc);
        a[6] = (bf16_t)(x1.z * sc); a[7] = (bf16_t)(x1.w * sc);
        qa[h2 * 4 + kb] = a;
      }
    }
  }

  f32x4 oacc[16];
#pragma unroll
  for (int nt = 0; nt < 16; ++nt) { f32x4 z = {0.f,0.f,0.f,0.f}; oacc[nt] = z; }
  float m_run0 = -INFINITY, l_run0 = 0.f;   // log2-domain, per lane (qrow=l15)
  float m_run1 = -INFINITY, l_run1 = 0.f;

  // K(0) landed (oldest 8 of the 16 outstanding; V's 8 still in flight)
  asm volatile("s_waitcnt vmcnt(8)\n\ts_barrier" ::: "memory");

  for (int c = 0; c < NCHUNK; ++c) {
    // ---- S = K Q^T, both halves share each kf read (permuted key rows)
    f32x4 s0[8], s1[8];
    __builtin_amdgcn_s_setprio(1);
#pragma unroll
    for (int t = 0; t < 2; ++t) {
      const char* Kt = smem + t * 16384;
#pragma unroll
      for (int nl = 0; nl < 4; ++nl) {
        const int rowA = (nl >> 1) * 32 + (l15 >> 2) * 8 + (nl & 1) * 4 + (l15 & 3);
        const int gx   = (rowA & 3) | (((rowA >> 3) & 3) << 2);  // == l15
        f32x4 a0 = {0.f, 0.f, 0.f, 0.f};
        f32x4 a1 = {0.f, 0.f, 0.f, 0.f};
#pragma unroll
        for (int j = 0; j < 4; ++j) {
          const uint32_t byte = (uint32_t)(rowA * 256) + ((j * 64 + lhi * 16) ^ (gx << 4));
          bf16x8 kf = *(const bf16x8*)(Kt + byte);
          a0 = __builtin_amdgcn_mfma_f32_16x16x32_bf16(kf, qa[j], a0, 0, 0, 0);
          a1 = __builtin_amdgcn_mfma_f32_16x16x32_bf16(kf, qa[4 + j], a1, 0, 0, 0);
        }
        s0[t * 4 + nl] = a0;
        s1[t * 4 + nl] = a1;
      }
    }
    __builtin_amdgcn_s_setprio(0);

    // V(c) landed (only outstanding loads) + all waves' QK reads done
    asm volatile("s_waitcnt vmcnt(0) lgkmcnt(0)\n\ts_barrier" ::: "memory");
    if (c + 1 < NCHUNK) {
      ISSUE_K(0, (c + 1) * CHUNK);
      ISSUE_K(16384, (c + 1) * CHUNK + 64);
    }

    // ---- softmax per half (log2 domain); exact skip of rescale when e==1
    bf16x8 pa0[4], pa1[4];
#define SOFTMAX_HALF(SA, PA, MRUN, LRUN, OBASE)                                \
    {                                                                          \
      f32x4 t0 = vmax4(SA[0], SA[1]), t1 = vmax4(SA[2], SA[3]);                \
      f32x4 t2 = vmax4(SA[4], SA[5]), t3 = vmax4(SA[6], SA[7]);                \
      f32x4 t4 = vmax4(vmax4(t0, t1), vmax4(t2, t3));                          \
      float mc = fmaxf(fmaxf(fmaxf(t4[0], t4[1]), t4[2]), t4[3]);              \
      mc = fmaxf(mc, __shfl_xor(mc, 16, 64));                                  \
      mc = fmaxf(mc, __shfl_xor(mc, 32, 64));                                  \
      const bool skip = __all(mc <= MRUN);                                     \
      const float mn = fmaxf(MRUN, mc);                                        \
      const float e  = exp2_fast(MRUN - mn);                                   \
      MRUN = mn;                                                               \
      f32x4 pe[8];                                                             \
      _Pragma("unroll")                                                        \
      for (int nt = 0; nt < 8; ++nt)                                           \
        _Pragma("unroll")                                                      \
        for (int r = 0; r < 4; ++r) {                                          \
          const float p = exp2_fast(SA[nt][r] - mc);                           \
          pe[nt][r] = p;                                                       \
          PA[(nt >> 2) * 2 + ((nt >> 1) & 1)][(nt & 1) * 4 + r] = (bf16_t)p;   \
        }                                                                      \
      f32x4 q0 = pe[0] + pe[1], q1 = pe[2] + pe[3];                            \
      f32x4 q2 = pe[4] + pe[5], q3 = pe[6] + pe[7];                            \
      f32x4 q4 = (q0 + q1) + (q2 + q3);                                        \
      float ps = (q4[0] + q4[1]) + (q4[2] + q4[3]);                            \
      ps += __shfl_xor(ps, 16, 64);                                            \
      ps += __shfl_xor(ps, 32, 64);                                            \
      if (skip) {                                                              \
        LRUN += ps;                                                            \
      } else {                                                                 \
        LRUN = LRUN * e + ps;                                                  \
        _Pragma("unroll")                                                      \
        for (int r = 0; r < 4; ++r) {                                          \
          const float er = __shfl(e, lhi * 4 + r, 16);                         \
          _Pragma("unroll")                                                    \
          for (int nt = 0; nt < 8; ++nt) oacc[(OBASE) + nt][r] *= er;          \
        }                                                                      \
      }                                                                        \
    }
    SOFTMAX_HALF(s0, pa0, m_run0, l_run0, 0)
    SOFTMAX_HALF(s1, pa1, m_run1, l_run1, 8)
#undef SOFTMAX_HALF

    // ---- O += P V, both halves share each vf read
    __builtin_amdgcn_s_setprio(1);
#pragma unroll
    for (int kv = 0; kv < 4; ++kv) {
#pragma unroll
      for (int nt = 0; nt < 8; ++nt) {
        const int dh = nt * 16 + l15;
        const uint32_t byte = (uint32_t)(32768 + dh * 256) +
            (((uint32_t)(kv * 64 + lhi * 16)) ^ ((dh & 15) << 4));
        bf16x8 vf = *(const bf16x8*)(smem + byte);
        oacc[nt]     = __builtin_amdgcn_mfma_f32_16x16x32_bf16(pa0[kv], vf, oacc[nt], 0, 0, 0);
        oacc[8 + nt] = __builtin_amdgcn_mfma_f32_16x16x32_bf16(pa1[kv], vf, oacc[8 + nt], 0, 0, 0);
      }
    }
    __builtin_amdgcn_s_setprio(0);

    // K(c+1) landed (only outstanding loads) + all waves' PV reads done
    asm volatile("s_waitcnt vmcnt(0) lgkmcnt(0)\n\ts_barrier" ::: "memory");
    if (c + 1 < NCHUNK) ISSUE_V((c + 1) * CHUNK);
  }

  // ---- epilogue: per-wave LDS transpose -> coalesced f32x4 stores, 2 passes
  {
    char* Ow = smem + wave * 8192;  // 16 rows x 512B per pass; 4 waves -> 32KB
#pragma unroll
    for (int h2 = 0; h2 < 2; ++h2) {
      const float lrl = h2 ? l_run1 : l_run0;
      float lr[4];
#pragma unroll
      for (int r = 0; r < 4; ++r) lr[r] = __shfl(lrl, lhi * 4 + r, 16);
#pragma unroll
      for (int nt = 0; nt < 8; ++nt)
#pragma unroll
        for (int r = 0; r < 4; ++r) {
          const int row = lhi * 4 + r;
          const int colb = (nt * 16 + l15) * 4;
          *(float*)(Ow + row * 512 + (colb ^ ((row & 7) << 4))) =
              oacc[h2 * 8 + nt][r] / (lr[r] + 1e-6f);
        }
      asm volatile("s_waitcnt lgkmcnt(0)" ::: "memory");  // wave-local only
      __builtin_amdgcn_sched_barrier(0);
#pragma unroll
      for (int p = 0; p < 8; ++p) {
        const int row = p * 2 + (lane >> 5);
        const int colb = (lane & 31) * 16;
        f32x4 val = *(const f32x4*)(Ow + row * 512 + (colb ^ ((row & 7) << 4)));
        *(f32x4*)((char*)(og + ((size_t)(b * SEQ + qrow0 + h2 * 16 + row)) * DMODEL +
                          h * DHEAD) + colb) = val;
      }
      asm volatile("s_waitcnt lgkmcnt(0)" ::: "memory");  // reads done before reuse
      __builtin_amdgcn_sched_barrier(0);
    }
  }
#undef ISSUE_K
#undef ISSUE_V
}

// ---------------- fallback (R2-proven): used if ws too small ----------------
__global__ __launch_bounds__(512, 2)
void fa_fwd_raw(const float* __restrict__ qg, const float* __restrict__ kg,
                const float* __restrict__ vg, float* __restrict__ og)
{
  __shared__ bf16_t Kl[CHUNK * DHEAD];
  __shared__ bf16_t Vt[DHEAD * CHUNK];
  const int tid = threadIdx.x, wave = tid >> 6, lane = tid & 63;
  const int l15 = lane & 15, lhi = lane >> 4;
  const int b = blockIdx.z, h = blockIdx.y;
  const int qrow0 = blockIdx.x * 128 + wave * 16;
  bf16x8 qa[4];
  {
    const float* qp = qg + ((size_t)(b * SEQ + qrow0 + l15)) * DMODEL + h * DHEAD;
    const float sc = 1.0f / 128.0f;
#pragma unroll
    for (int kb = 0; kb < 4; ++kb) {
      const float* p8 = qp + kb * 32 + lhi * 8;
      float4 x0 = *(const float4*)p8; float4 x1 = *(const float4*)(p8 + 4);
      bf16x8 a;
      a[0]=(bf16_t)(x0.x*sc); a[1]=(bf16_t)(x0.y*sc); a[2]=(bf16_t)(x0.z*sc); a[3]=(bf16_t)(x0.w*sc);
      a[4]=(bf16_t)(x1.x*sc); a[5]=(bf16_t)(x1.y*sc); a[6]=(bf16_t)(x1.z*sc); a[7]=(bf16_t)(x1.w*sc);
      qa[kb] = a;
    }
  }
  f32x4 oacc[8];
#pragma unroll
  for (int nt = 0; nt < 8; ++nt) { f32x4 z = {0.f,0.f,0.f,0.f}; oacc[nt] = z; }
  float m_run[4] = {-INFINITY,-INFINITY,-INFINITY,-INFINITY};
  float l_run[4] = {0.f,0.f,0.f,0.f};
  const float* kbp = kg + ((size_t)b * SEQ) * DMODEL + h * DHEAD;
  const float* vbp = vg + ((size_t)b * SEQ) * DMODEL + h * DHEAD;
  const int krow16 = tid >> 5, kc4 = (tid & 31) * 4;
  const int vdh = tid & 127, vkg = (tid >> 7) * 8;
  for (int c = 0; c < NCHUNK; ++c) {
    const int key0 = c * CHUNK;
#pragma unroll
    for (int pass = 0; pass < 8; ++pass) {
      const int key = pass * 16 + krow16;
      const float4 x = *(const float4*)(kbp + (size_t)(key0 + key) * DMODEL + kc4);
      bf16x4 y; y[0]=(bf16_t)x.x; y[1]=(bf16_t)x.y; y[2]=(bf16_t)x.z; y[3]=(bf16_t)x.w;
      *(bf16x4*)((char*)Kl + swz(key, kc4 * 2)) = y;
    }
#pragma unroll
    for (int it = 0; it < 4; ++it) {
      const int kb0 = it * 32 + vkg;
      const float* vp = vbp + (size_t)(key0 + kb0) * DMODEL + vdh;
      bf16x8 y;
#pragma unroll
      for (int j = 0; j < 8; ++j) y[j] = (bf16_t)vp[(size_t)j * DMODEL];
      *(bf16x8*)((char*)Vt + swz(vdh, kb0 * 2)) = y;
    }
    __syncthreads();
    f32x4 sacc[8];
#pragma unroll
    for (int nt = 0; nt < 8; ++nt) {
      f32x4 acc = {0.f,0.f,0.f,0.f};
      const int key = nt * 16 + l15;
#pragma unroll
      for (int kb = 0; kb < 4; ++kb) {
        bf16x8 bfr = *(const bf16x8*)((const char*)Kl + swz(key, (kb*32+lhi*8)*2));
        acc = __builtin_amdgcn_mfma_f32_16x16x32_bf16(qa[kb], bfr, acc, 0, 0, 0);
      }
      sacc[nt] = acc;
    }
    __syncthreads();
    float mc[4];
#pragma unroll
    for (int r = 0; r < 4; ++r) {
      float m0 = sacc[0][r];
#pragma unroll
      for (int nt = 1; nt < 8; ++nt) m0 = fmaxf(m0, sacc[nt][r]);
      mc[r] = m0;
    }
#pragma unroll
    for (int sh = 1; sh < 16; sh <<= 1)
#pragma unroll
      for (int r = 0; r < 4; ++r) mc[r] = fmaxf(mc[r], __shfl_xor(mc[r], sh, 64));
    float esc[4], psum[4];
#pragma unroll
    for (int r = 0; r < 4; ++r) {
      const float mn = fmaxf(m_run[r], mc[r]);
      esc[r] = __expf(m_run[r] - mn); m_run[r] = mn; psum[r] = 0.f;
    }
    bf16_t* Pw = Kl + wave * (16 * 128);
#pragma unroll
    for (int nt = 0; nt < 8; ++nt)
#pragma unroll
      for (int r = 0; r < 4; ++r) {
        const float p = __expf(sacc[nt][r] - mc[r]);
        psum[r] += p;
        const int row = lhi * 4 + r;
        *(bf16_t*)((char*)Pw + swz(row, (nt*16+l15)*2)) = (bf16_t)p;
      }
#pragma unroll
    for (int sh = 1; sh < 16; sh <<= 1)
#pragma unroll
      for (int r = 0; r < 4; ++r) psum[r] += __shfl_xor(psum[r], sh, 64);
#pragma unroll
    for (int r = 0; r < 4; ++r) l_run[r] = l_run[r] * esc[r] + psum[r];
#pragma unroll
    for (int nt = 0; nt < 8; ++nt) {
      f32x4 o = oacc[nt];
      o[0]*=esc[0]; o[1]*=esc[1]; o[2]*=esc[2]; o[3]*=esc[3];
      oacc[nt] = o;
    }
    asm volatile("s_waitcnt lgkmcnt(0)" ::: "memory");
    __builtin_amdgcn_sched_barrier(0);
#pragma unroll
    for (int kb = 0; kb < 4; ++kb) {
      bf16x8 pf = *(const bf16x8*)((const char*)Pw + swz(l15, (kb*32+lhi*8)*2));
#pragma unroll
      for (int nt = 0; nt < 8; ++nt) {
        const int dh = nt * 16 + l15;
        bf16x8 vf = *(const bf16x8*)((const char*)Vt + swz(dh, (kb*32+lhi*8)*2));
        oacc[nt] = __builtin_amdgcn_mfma_f32_16x16x32_bf16(pf, vf, oacc[nt], 0, 0, 0);
      }
    }
    __syncthreads();
  }
#pragma unroll
  for (int nt = 0; nt < 8; ++nt)
#pragma unroll
    for (int r = 0; r < 4; ++r) {
      const int row = lhi * 4 + r;
      og[((size_t)(b * SEQ + qrow0 + row)) * DMODEL + h * DHEAD + nt * 16 + l15] =
          oacc[nt][r] / (l_run[r] + 1e-6f);
    }
}

extern "C" void kernel_launch(void* const* d_in, const int* in_sizes, int n_in,
                              void* d_out, int out_size, void* d_ws, size_t ws_size,
                              hipStream_t stream) {
  const float* q = (const float*)d_in[0];
  const float* k = (const float*)d_in[1];
  const float* v = (const float*)d_in[2];
  float* o = (float*)d_out;
  const int B = in_sizes[0] / (SEQ * DMODEL);
  const size_t kv_bytes = (size_t)B * NHEADS * SEQ * DHEAD * 2;  // 33.5MB @ B=2
  if (ws_size >= 2 * kv_bytes) {
    bf16_t* kb = (bf16_t*)d_ws;
    bf16_t* vb = (bf16_t*)((char*)d_ws + kv_bytes);
    const int nthr = (int)(((size_t)B * SEQ * DMODEL) / 8);
    prep_k<<<nthr / 256, 256, 0, stream>>>(k, kb);
    dim3 gv(SEQ / 128, NHEADS, B);
    prep_v<<<gv, 256, 0, stream>>>(v, vb);
    dim3 grid(SEQ / QBLK, NHEADS, B);
    fa_fwd_p<<<grid, 256, 0, stream>>>(q, kb, vb, o);
  } else {
    dim3 grid(SEQ / 128, NHEADS, B);
    fa_fwd_raw<<<grid, 512, 0, stream>>>(q, k, v, o);
  }
}